// Round 1
// baseline (315.397 us; speedup 1.0000x reference)
//
#include <hip/hip_runtime.h>
#include <hip/hip_bf16.h>
#include <stdint.h>

typedef __bf16 bf16_t;
typedef __bf16 bf16x8 __attribute__((ext_vector_type(8)));
typedef __bf16 bf16x4 __attribute__((ext_vector_type(4)));
typedef float f32x4 __attribute__((ext_vector_type(4)));

#define DEVI static __device__ __forceinline__

// async global->LDS, 16B per lane. LDS dest = wave-uniform base + lane*16 (HW).
DEVI void gload_lds16(const void* g, void* lds) {
  __builtin_amdgcn_global_load_lds(
      (const __attribute__((address_space(1))) unsigned int*)g,
      (__attribute__((address_space(3))) unsigned int*)lds, 16, 0, 0);
}

// ---------------- f32 -> bf16 conversion (vectorized) ----------------
__global__ void cvt4(const float* __restrict__ in, bf16_t* __restrict__ out, int n4) {
  int i = blockIdx.x * blockDim.x + threadIdx.x;
  if (i < n4) {
    float4 v = ((const float4*)in)[i];
    bf16x4 o;
    o[0] = (bf16_t)v.x; o[1] = (bf16_t)v.y; o[2] = (bf16_t)v.z; o[3] = (bf16_t)v.w;
    ((bf16x4*)out)[i] = o;
  }
}

// ---------------- GEMM: C[M,N] = A[M,K] @ B[N,K]^T + bias ----------------
// EPI: 0 = bf16 row-major out, 1 = f32 row-major out, 2 = QKV scatter
// 128x128 tile, BK=64, 4 waves (2x2), 16x16x32 bf16 MFMA, contiguous-K frags.
template <int EPI>
__global__ __launch_bounds__(256) void gemm_bt(
    const bf16_t* __restrict__ A, const bf16_t* __restrict__ B,
    const float* __restrict__ bias, void* __restrict__ Cout,
    int M, int N, int K,
    bf16_t* __restrict__ qo, bf16_t* __restrict__ ko, bf16_t* __restrict__ vo) {
  __shared__ alignas(16) bf16_t As[128][64];
  __shared__ alignas(16) bf16_t Bs[128][64];
  const int tid = threadIdx.x;
  const int wave = tid >> 6, lane = tid & 63;
  const int lr = lane & 15, lg = lane >> 4;
  const int wr = wave >> 1, wc = wave & 1;
  const int bm = blockIdx.x * 128, bn = blockIdx.y * 128;

  f32x4 acc[4][4];
#pragma unroll
  for (int m = 0; m < 4; m++)
#pragma unroll
    for (int n = 0; n < 4; n++) acc[m][n] = (f32x4){0.f, 0.f, 0.f, 0.f};

  const int srow = tid >> 3;          // 0..31, +32 per staging iter
  const int scol = (tid & 7) * 8;     // element col within BK=64

  for (int k0 = 0; k0 < K; k0 += 64) {
#pragma unroll
    for (int i = 0; i < 4; i++) {
      const bf16_t* ga = A + (size_t)(bm + srow + i * 32) * K + (k0 + scol);
      gload_lds16(ga, (char*)As + i * 4096 + wave * 1024);
    }
#pragma unroll
    for (int i = 0; i < 4; i++) {
      const bf16_t* gb = B + (size_t)(bn + srow + i * 32) * K + (k0 + scol);
      gload_lds16(gb, (char*)Bs + i * 4096 + wave * 1024);
    }
    __syncthreads();  // compiler emits vmcnt(0) drain before barrier
#pragma unroll
    for (int kk = 0; kk < 64; kk += 32) {
      bf16x8 af[4], bfr[4];
#pragma unroll
      for (int m = 0; m < 4; m++)
        af[m] = *(const bf16x8*)&As[wr * 64 + m * 16 + lr][kk + lg * 8];
#pragma unroll
      for (int n = 0; n < 4; n++)
        bfr[n] = *(const bf16x8*)&Bs[wc * 64 + n * 16 + lr][kk + lg * 8];
#pragma unroll
      for (int m = 0; m < 4; m++)
#pragma unroll
        for (int n = 0; n < 4; n++)
          acc[m][n] = __builtin_amdgcn_mfma_f32_16x16x32_bf16(af[m], bfr[n], acc[m][n], 0, 0, 0);
    }
    __syncthreads();
  }

  // Epilogue. C/D layout: row = 4*lg + i, col = lr (within each 16x16 frag).
#pragma unroll
  for (int n = 0; n < 4; n++) {
    const int gc = bn + wc * 64 + n * 16 + lr;
    const float bv = bias[gc];
#pragma unroll
    for (int m = 0; m < 4; m++) {
#pragma unroll
      for (int i = 0; i < 4; i++) {
        const int gr = bm + wr * 64 + m * 16 + lg * 4 + i;
        float v = acc[m][n][i] + bv;
        if (EPI == 0) {
          ((bf16_t*)Cout)[(size_t)gr * N + gc] = (bf16_t)v;
        } else if (EPI == 1) {
          ((float*)Cout)[(size_t)gr * N + gc] = v;
        } else {
          const int which = gc >> 10, e = gc & 1023, h = e >> 6, d = e & 63;
          const int b = gr >> 10, t = gr & 1023;
          const int bh = b * 16 + h;
          if (which == 0)
            qo[((size_t)bh * 1024 + t) * 64 + d] = (bf16_t)(v * 0.125f);  // fold 1/sqrt(64)
          else if (which == 1)
            ko[((size_t)bh * 1024 + t) * 64 + d] = (bf16_t)v;
          else
            vo[((size_t)bh * 64 + d) * 1024 + t] = (bf16_t)v;  // V transposed
        }
      }
    }
  }
}

// ---------------- causal flash attention ----------------
// grid: (16 q-tiles of 64, 128 b*h). 4 waves, each owns 16 q rows.
// Q pre-scaled by 0.125. K: [bh][t][64]. Vt: [bh][64][t]. Out: [b*t][1024] bf16.
__global__ __launch_bounds__(256) void attn_fwd(
    const bf16_t* __restrict__ Q, const bf16_t* __restrict__ K,
    const bf16_t* __restrict__ Vt, bf16_t* __restrict__ Out) {
  __shared__ alignas(16) bf16_t Ks[64][64];
  __shared__ alignas(16) bf16_t Vs[64][64];     // [d][kv]
  __shared__ alignas(16) bf16_t Ps[4][16][64];  // per-wave P
  const int tid = threadIdx.x, wave = tid >> 6, lane = tid & 63;
  const int lr = lane & 15, lg = lane >> 4;
  const int bh = blockIdx.y;
  const int b = bh >> 4, h = bh & 15;
  const int q0 = blockIdx.x * 64;
  const bf16_t* Qb = Q + (size_t)bh * 1024 * 64;
  const bf16_t* Kb = K + (size_t)bh * 1024 * 64;
  const bf16_t* Vb = Vt + (size_t)bh * 64 * 1024;

  const int qr = q0 + wave * 16;
  bf16x8 qf[2];
#pragma unroll
  for (int kk = 0; kk < 2; kk++)
    qf[kk] = *(const bf16x8*)&Qb[(size_t)(qr + lr) * 64 + kk * 32 + lg * 8];

  f32x4 acc[4];
#pragma unroll
  for (int n = 0; n < 4; n++) acc[n] = (f32x4){0.f, 0.f, 0.f, 0.f};
  float m_i[4], l_i[4];
#pragma unroll
  for (int i = 0; i < 4; i++) { m_i[i] = -1e30f; l_i[i] = 0.f; }

  const int srow = tid >> 3;
  const int scol = (tid & 7) * 8;
  const int nt = blockIdx.x + 1;

  for (int t = 0; t < nt; t++) {
#pragma unroll
    for (int i = 0; i < 2; i++) {
      const bf16_t* gk = Kb + (size_t)(t * 64 + srow + i * 32) * 64 + scol;
      gload_lds16(gk, (char*)Ks + i * 4096 + wave * 1024);
    }
#pragma unroll
    for (int i = 0; i < 2; i++) {
      const bf16_t* gv = Vb + (size_t)(srow + i * 32) * 1024 + t * 64 + scol;
      gload_lds16(gv, (char*)Vs + i * 4096 + wave * 1024);
    }
    __syncthreads();

    // S = Q @ K^T  (16q x 64kv per wave)
    f32x4 s[4];
#pragma unroll
    for (int n = 0; n < 4; n++) s[n] = (f32x4){0.f, 0.f, 0.f, 0.f};
#pragma unroll
    for (int kk = 0; kk < 2; kk++) {
#pragma unroll
      for (int n = 0; n < 4; n++) {
        bf16x8 bb = *(const bf16x8*)&Ks[n * 16 + lr][kk * 32 + lg * 8];
        s[n] = __builtin_amdgcn_mfma_f32_16x16x32_bf16(qf[kk], bb, s[n], 0, 0, 0);
      }
    }
    if (t == nt - 1) {  // only diagonal tile needs the causal mask
#pragma unroll
      for (int n = 0; n < 4; n++)
#pragma unroll
        for (int i = 0; i < 4; i++) {
          int kv = t * 64 + n * 16 + lr;
          int qa = qr + lg * 4 + i;
          if (kv > qa) s[n][i] = -1e30f;
        }
    }
    // online softmax: row r = 4*lg+i lives on the 16 lanes sharing lg
    float p[4][4];
#pragma unroll
    for (int i = 0; i < 4; i++) {
      float mx = fmaxf(fmaxf(s[0][i], s[1][i]), fmaxf(s[2][i], s[3][i]));
#pragma unroll
      for (int o = 1; o < 16; o <<= 1) mx = fmaxf(mx, __shfl_xor(mx, o, 64));
      float mnew = fmaxf(m_i[i], mx);
      float alpha = __expf(m_i[i] - mnew);
      float rs = 0.f;
#pragma unroll
      for (int n = 0; n < 4; n++) {
        float pv = __expf(s[n][i] - mnew);
        p[n][i] = pv;
        rs += pv;
      }
#pragma unroll
      for (int o = 1; o < 16; o <<= 1) rs += __shfl_xor(rs, o, 64);
      l_i[i] = l_i[i] * alpha + rs;
      m_i[i] = mnew;
#pragma unroll
      for (int n = 0; n < 4; n++) acc[n][i] *= alpha;
    }
    // P -> per-wave LDS (re-fragment for PV). Same-wave ds ops are in-order.
#pragma unroll
    for (int n = 0; n < 4; n++)
#pragma unroll
      for (int i = 0; i < 4; i++) Ps[wave][lg * 4 + i][n * 16 + lr] = (bf16_t)p[n][i];
    // O += P @ V
#pragma unroll
    for (int kk = 0; kk < 2; kk++) {
      bf16x8 pa = *(const bf16x8*)&Ps[wave][lr][kk * 32 + lg * 8];
#pragma unroll
      for (int n = 0; n < 4; n++) {
        bf16x8 vb = *(const bf16x8*)&Vs[n * 16 + lr][kk * 32 + lg * 8];
        acc[n] = __builtin_amdgcn_mfma_f32_16x16x32_bf16(pa, vb, acc[n], 0, 0, 0);
      }
    }
    __syncthreads();
  }

#pragma unroll
  for (int i = 0; i < 4; i++) {
    float inv = 1.f / l_i[i];
    int qa = qr + lg * 4 + i;
#pragma unroll
    for (int n = 0; n < 4; n++)
      Out[((size_t)b * 1024 + qa) * 1024 + h * 64 + n * 16 + lr] = (bf16_t)(acc[n][i] * inv);
  }
}

// ---------------- launch ----------------
extern "C" void kernel_launch(void* const* d_in, const int* in_sizes, int n_in,
                              void* d_out, int out_size, void* d_ws, size_t ws_size,
                              hipStream_t stream) {
  const float* x = (const float*)d_in[0];
  const float* w_in = (const float*)d_in[1];
  const float* b_in = (const float*)d_in[2];
  const float* w_out = (const float*)d_in[3];
  const float* b_out = (const float*)d_in[4];
  const float* w_c = (const float*)d_in[5];
  const float* b_c = (const float*)d_in[6];
  float* out = (float*)d_out;

  const int M = 8192, E = 1024, N3 = 3072;
  char* ws = (char*)d_ws;
  size_t off = 0;
  auto alloc = [&](size_t bytes) {
    char* p = ws + off;
    off += (bytes + 255) & ~(size_t)255;
    return p;
  };
  bf16_t* xb = (bf16_t*)alloc((size_t)M * E * 2);
  bf16_t* wqb = (bf16_t*)alloc((size_t)N3 * E * 2);
  bf16_t* wob = (bf16_t*)alloc((size_t)E * E * 2);
  bf16_t* wcb = (bf16_t*)alloc((size_t)E * E * 2);
  bf16_t* Qs = (bf16_t*)alloc((size_t)M * E * 2);
  bf16_t* Kc = (bf16_t*)alloc((size_t)M * E * 2);
  bf16_t* Vt = (bf16_t*)alloc((size_t)M * E * 2);
  bf16_t* AO = (bf16_t*)alloc((size_t)M * E * 2);
  bf16_t* H1 = (bf16_t*)alloc((size_t)M * E * 2);
  // total ~111 MB of d_ws

  cvt4<<<(M * E / 4 + 255) / 256, 256, 0, stream>>>(x, xb, M * E / 4);
  cvt4<<<(N3 * E / 4 + 255) / 256, 256, 0, stream>>>(w_in, wqb, N3 * E / 4);
  cvt4<<<(E * E / 4 + 255) / 256, 256, 0, stream>>>(w_out, wob, E * E / 4);
  cvt4<<<(E * E / 4 + 255) / 256, 256, 0, stream>>>(w_c, wcb, E * E / 4);

  gemm_bt<2><<<dim3(M / 128, N3 / 128), 256, 0, stream>>>(
      xb, wqb, b_in, nullptr, M, N3, E, Qs, Kc, Vt);
  attn_fwd<<<dim3(16, 128), 256, 0, stream>>>(Qs, Kc, Vt, AO);
  gemm_bt<0><<<dim3(M / 128, E / 128), 256, 0, stream>>>(
      AO, wob, b_out, H1, M, E, E, nullptr, nullptr, nullptr);
  gemm_bt<1><<<dim3(M / 128, E / 128), 256, 0, stream>>>(
      H1, wcb, b_c, out, M, E, E, nullptr, nullptr, nullptr);
}

// Round 2
// 231.765 us; speedup vs baseline: 1.3608x; 1.3608x over previous
//
#include <hip/hip_runtime.h>
#include <hip/hip_bf16.h>
#include <stdint.h>

typedef __bf16 bf16_t;
typedef __bf16 bf16x8 __attribute__((ext_vector_type(8)));
typedef __bf16 bf16x4 __attribute__((ext_vector_type(4)));
typedef float f32x4 __attribute__((ext_vector_type(4)));

#define DEVI static __device__ __forceinline__

// async global->LDS, 16B per lane. LDS dest = wave-uniform base + lane*16 (HW).
DEVI void gload_lds16(const void* g, void* lds) {
  __builtin_amdgcn_global_load_lds(
      (const __attribute__((address_space(1))) unsigned int*)g,
      (__attribute__((address_space(3))) unsigned int*)lds, 16, 0, 0);
}

// ---------------- f32 -> bf16 conversion (vectorized) ----------------
__global__ void cvt4(const float* __restrict__ in, bf16_t* __restrict__ out, int n4) {
  int i = blockIdx.x * blockDim.x + threadIdx.x;
  if (i < n4) {
    float4 v = ((const float4*)in)[i];
    bf16x4 o;
    o[0] = (bf16_t)v.x; o[1] = (bf16_t)v.y; o[2] = (bf16_t)v.z; o[3] = (bf16_t)v.w;
    ((bf16x4*)out)[i] = o;
  }
}

// ---------------- GEMM: C[M,N] = A[M,K] @ B[N,K]^T + bias ----------------
// EPI: 0 = bf16 row-major out, 1 = f32 row-major out, 2 = QKV scatter
template <int EPI>
__global__ __launch_bounds__(256) void gemm_bt(
    const bf16_t* __restrict__ A, const bf16_t* __restrict__ B,
    const float* __restrict__ bias, void* __restrict__ Cout,
    int M, int N, int K,
    bf16_t* __restrict__ qo, bf16_t* __restrict__ ko, bf16_t* __restrict__ vo) {
  __shared__ alignas(16) bf16_t As[128][64];
  __shared__ alignas(16) bf16_t Bs[128][64];
  const int tid = threadIdx.x;
  const int wave = tid >> 6, lane = tid & 63;
  const int lr = lane & 15, lg = lane >> 4;
  const int wr = wave >> 1, wc = wave & 1;
  const int bm = blockIdx.x * 128, bn = blockIdx.y * 128;

  f32x4 acc[4][4];
#pragma unroll
  for (int m = 0; m < 4; m++)
#pragma unroll
    for (int n = 0; n < 4; n++) acc[m][n] = (f32x4){0.f, 0.f, 0.f, 0.f};

  const int srow = tid >> 3;          // 0..31, +32 per staging iter
  const int scol = (tid & 7) * 8;     // element col within BK=64

  for (int k0 = 0; k0 < K; k0 += 64) {
#pragma unroll
    for (int i = 0; i < 4; i++) {
      const bf16_t* ga = A + (size_t)(bm + srow + i * 32) * K + (k0 + scol);
      gload_lds16(ga, (char*)As + i * 4096 + wave * 1024);
    }
#pragma unroll
    for (int i = 0; i < 4; i++) {
      const bf16_t* gb = B + (size_t)(bn + srow + i * 32) * K + (k0 + scol);
      gload_lds16(gb, (char*)Bs + i * 4096 + wave * 1024);
    }
    __syncthreads();
#pragma unroll
    for (int kk = 0; kk < 64; kk += 32) {
      bf16x8 af[4], bfr[4];
#pragma unroll
      for (int m = 0; m < 4; m++)
        af[m] = *(const bf16x8*)&As[wr * 64 + m * 16 + lr][kk + lg * 8];
#pragma unroll
      for (int n = 0; n < 4; n++)
        bfr[n] = *(const bf16x8*)&Bs[wc * 64 + n * 16 + lr][kk + lg * 8];
#pragma unroll
      for (int m = 0; m < 4; m++)
#pragma unroll
        for (int n = 0; n < 4; n++)
          acc[m][n] = __builtin_amdgcn_mfma_f32_16x16x32_bf16(af[m], bfr[n], acc[m][n], 0, 0, 0);
    }
    __syncthreads();
  }

  // Epilogue. C/D layout: row = 4*lg + i, col = lr (within each 16x16 frag).
#pragma unroll
  for (int n = 0; n < 4; n++) {
    const int gc = bn + wc * 64 + n * 16 + lr;
    const float bv = bias[gc];
#pragma unroll
    for (int m = 0; m < 4; m++) {
#pragma unroll
      for (int i = 0; i < 4; i++) {
        const int gr = bm + wr * 64 + m * 16 + lg * 4 + i;
        float v = acc[m][n][i] + bv;
        if (EPI == 0) {
          ((bf16_t*)Cout)[(size_t)gr * N + gc] = (bf16_t)v;
        } else if (EPI == 1) {
          ((float*)Cout)[(size_t)gr * N + gc] = v;
        } else {
          const int which = gc >> 10, e = gc & 1023, h = e >> 6, d = e & 63;
          const int b = gr >> 10, t = gr & 1023;
          const int bh = b * 16 + h;
          if (which == 0)
            qo[((size_t)bh * 1024 + t) * 64 + d] = (bf16_t)(v * 0.125f);  // fold 1/sqrt(64)
          else if (which == 1)
            ko[((size_t)bh * 1024 + t) * 64 + d] = (bf16_t)v;
          else
            vo[((size_t)bh * 64 + d) * 1024 + t] = (bf16_t)v;  // V transposed
        }
      }
    }
  }
}

// ---------------- causal flash attention (v2) ----------------
// grid (8, 128). Block handles q-tile pair {bx, 15-bx}: constant 17 KV-tile
// iterations. 4 waves x 16 q-rows. Swapped QK^T: S[kv][q] with q on lane idx
// -> softmax row is (nearly) lane-local. K/V double-buffered, XOR-swizzled
// (pre-swizzled global source since global_load_lds writes linearly).
// Q pre-scaled by 0.125. K: [bh][t][64]. Vt: [bh][64][t]. Out: [b*t][1024] bf16.
__global__ __launch_bounds__(256) void attn_fwd(
    const bf16_t* __restrict__ Q, const bf16_t* __restrict__ K,
    const bf16_t* __restrict__ Vt, bf16_t* __restrict__ Out) {
  __shared__ alignas(16) bf16_t Ks[2][64][64];
  __shared__ alignas(16) bf16_t Vs[2][64][64];  // [d][kv]
  __shared__ alignas(16) bf16_t Ps[4][16][64];  // per-wave P[q][kv], swizzled
  const int tid = threadIdx.x, wave = tid >> 6, lane = tid & 63;
  const int lr = lane & 15, lg = lane >> 4;
  const int bx = blockIdx.x;  // 0..7 -> q-tiles {bx, 15-bx}
  const int bh = blockIdx.y;
  const int b = bh >> 4, h = bh & 15;
  const bf16_t* Qb = Q + (size_t)bh * 65536;
  const bf16_t* Kb = K + (size_t)bh * 65536;
  const bf16_t* Vb = Vt + (size_t)bh * 65536;

  const int srow = tid >> 3;                     // LDS row this thread fills
  const int schunk = (tid & 7) ^ (srow & 7);     // pre-swizzled global 16B chunk

  auto stage = [&](int bufn, int t) {
#pragma unroll
    for (int i = 0; i < 2; i++) {
      const bf16_t* g = Kb + (size_t)(t * 64 + srow + i * 32) * 64 + schunk * 8;
      gload_lds16(g, (char*)Ks[bufn] + i * 4096 + wave * 1024);
    }
#pragma unroll
    for (int i = 0; i < 2; i++) {
      const bf16_t* g = Vb + (size_t)(srow + i * 32) * 1024 + t * 64 + schunk * 8;
      gload_lds16(g, (char*)Vs[bufn] + i * 4096 + wave * 1024);
    }
  };
  // swizzled b128 read of row r, k-chunk kk (elements kk*32+lg*8 .. +7)
  auto ldtile = [&](const bf16_t (*tile)[64], int r, int kk) -> bf16x8 {
    return *(const bf16x8*)((const char*)tile + r * 128 +
                            ((((kk << 2) + lg) ^ (r & 7)) << 4));
  };
  char* psb = (char*)Ps + wave * 2048;

  int qt = bx;
  int qr = qt * 64 + wave * 16;
  bf16x8 qf[2];
#pragma unroll
  for (int kk = 0; kk < 2; kk++)
    qf[kk] = *(const bf16x8*)&Qb[(size_t)(qr + lr) * 64 + kk * 32 + lg * 8];

  f32x4 acc[4];
#pragma unroll
  for (int n = 0; n < 4; n++) acc[n] = (f32x4){0.f, 0.f, 0.f, 0.f};
  float m_s = -1e30f, l_s = 0.f;

  stage(0, 0);
  int buf = 0;
  for (int it = 0; it < 17; ++it) {
    const int t = (it <= bx) ? it : it - bx - 1;
    const bool lastOfPhase = (it == bx) || (it == 16);
    __syncthreads();  // implicit vmcnt(0): buf's tile (staged last iter) ready
    if (it < 16) {
      const int tn = (it + 1 <= bx) ? it + 1 : it - bx;
      stage(buf ^ 1, tn);  // async, overlaps this iteration's compute
    }

    // S = K @ Q^T per wave: s[n][i] = S[kv = 16n+4lg+i][q = lr]
    f32x4 s[4];
#pragma unroll
    for (int n = 0; n < 4; n++) s[n] = (f32x4){0.f, 0.f, 0.f, 0.f};
#pragma unroll
    for (int kk = 0; kk < 2; kk++)
#pragma unroll
      for (int n = 0; n < 4; n++) {
        bf16x8 kf = ldtile(Ks[buf], n * 16 + lr, kk);
        s[n] = __builtin_amdgcn_mfma_f32_16x16x32_bf16(kf, qf[kk], s[n], 0, 0, 0);
      }

    if (lastOfPhase) {  // diagonal tile: causal mask
      const int qa = qr + lr;
#pragma unroll
      for (int n = 0; n < 4; n++)
#pragma unroll
        for (int i = 0; i < 4; i++) {
          const int kv = t * 64 + n * 16 + 4 * lg + i;
          if (kv > qa) s[n][i] = -1e30f;
        }
    }

    // online softmax for q = lr (16 in-lane values + 2 shfl over lg groups)
    float mx = s[0][0];
#pragma unroll
    for (int n = 0; n < 4; n++)
#pragma unroll
      for (int i = 0; i < 4; i++) mx = fmaxf(mx, s[n][i]);
    mx = fmaxf(mx, __shfl_xor(mx, 16, 64));
    mx = fmaxf(mx, __shfl_xor(mx, 32, 64));
    const float mnew = fmaxf(m_s, mx);
    const float alpha = __expf(m_s - mnew);
    m_s = mnew;
    float p[4][4];
    float rs = 0.f;
#pragma unroll
    for (int n = 0; n < 4; n++)
#pragma unroll
      for (int i = 0; i < 4; i++) {
        const float pv = __expf(s[n][i] - mnew);
        p[n][i] = pv;
        rs += pv;
      }
    rs += __shfl_xor(rs, 16, 64);
    rs += __shfl_xor(rs, 32, 64);
    l_s = l_s * alpha + rs;
    // rescale acc rows (acc row q = qr + 4lg + i; alpha lives on lane q%16)
#pragma unroll
    for (int i = 0; i < 4; i++) {
      const float ai = __shfl(alpha, 4 * lg + i, 64);
#pragma unroll
      for (int n = 0; n < 4; n++) acc[n][i] *= ai;
    }

    // P -> per-wave LDS (swizzled both sides), re-fragment for PV
#pragma unroll
    for (int n = 0; n < 4; n++) {
      bf16x4 pw;
#pragma unroll
      for (int i = 0; i < 4; i++) pw[i] = (bf16_t)p[n][i];
      *(bf16x4*)(psb + lr * 128 + ((((n << 1) + (lg >> 1)) ^ (lr & 7)) << 4) +
                 ((lg & 1) << 3)) = pw;
    }
    // O += P @ V : acc[n][i] = O[q = qr+4lg+i][d = 16n+lr]
#pragma unroll
    for (int kk = 0; kk < 2; kk++) {
      bf16x8 pa = *(const bf16x8*)(psb + lr * 128 +
                                   ((((kk << 2) + lg) ^ (lr & 7)) << 4));
#pragma unroll
      for (int n = 0; n < 4; n++) {
        bf16x8 vb = ldtile(Vs[buf], n * 16 + lr, kk);
        acc[n] = __builtin_amdgcn_mfma_f32_16x16x32_bf16(pa, vb, acc[n], 0, 0, 0);
      }
    }

    if (lastOfPhase) {
      const float invl = 1.f / l_s;
#pragma unroll
      for (int i = 0; i < 4; i++) {
        const float inv_i = __shfl(invl, 4 * lg + i, 64);
        const int qa = qr + 4 * lg + i;
#pragma unroll
        for (int n = 0; n < 4; n++)
          Out[((size_t)b * 1024 + qa) * 1024 + h * 64 + n * 16 + lr] =
              (bf16_t)(acc[n][i] * inv_i);
      }
      if (it == bx) {  // switch to phase B (q-tile 15-bx)
        qt = 15 - bx;
        qr = qt * 64 + wave * 16;
#pragma unroll
        for (int kk = 0; kk < 2; kk++)
          qf[kk] = *(const bf16x8*)&Qb[(size_t)(qr + lr) * 64 + kk * 32 + lg * 8];
#pragma unroll
        for (int n = 0; n < 4; n++) acc[n] = (f32x4){0.f, 0.f, 0.f, 0.f};
        m_s = -1e30f;
        l_s = 0.f;
      }
    }
    buf ^= 1;
  }
}

// ---------------- launch ----------------
extern "C" void kernel_launch(void* const* d_in, const int* in_sizes, int n_in,
                              void* d_out, int out_size, void* d_ws, size_t ws_size,
                              hipStream_t stream) {
  const float* x = (const float*)d_in[0];
  const float* w_in = (const float*)d_in[1];
  const float* b_in = (const float*)d_in[2];
  const float* w_out = (const float*)d_in[3];
  const float* b_out = (const float*)d_in[4];
  const float* w_c = (const float*)d_in[5];
  const float* b_c = (const float*)d_in[6];
  float* out = (float*)d_out;

  const int M = 8192, E = 1024, N3 = 3072;
  char* ws = (char*)d_ws;
  size_t off = 0;
  auto alloc = [&](size_t bytes) {
    char* p = ws + off;
    off += (bytes + 255) & ~(size_t)255;
    return p;
  };
  bf16_t* xb = (bf16_t*)alloc((size_t)M * E * 2);
  bf16_t* wqb = (bf16_t*)alloc((size_t)N3 * E * 2);
  bf16_t* wob = (bf16_t*)alloc((size_t)E * E * 2);
  bf16_t* wcb = (bf16_t*)alloc((size_t)E * E * 2);
  bf16_t* Qs = (bf16_t*)alloc((size_t)M * E * 2);
  bf16_t* Kc = (bf16_t*)alloc((size_t)M * E * 2);
  bf16_t* Vt = (bf16_t*)alloc((size_t)M * E * 2);
  bf16_t* AO = (bf16_t*)alloc((size_t)M * E * 2);
  bf16_t* H1 = (bf16_t*)alloc((size_t)M * E * 2);

  cvt4<<<(M * E / 4 + 255) / 256, 256, 0, stream>>>(x, xb, M * E / 4);
  cvt4<<<(N3 * E / 4 + 255) / 256, 256, 0, stream>>>(w_in, wqb, N3 * E / 4);
  cvt4<<<(E * E / 4 + 255) / 256, 256, 0, stream>>>(w_out, wob, E * E / 4);
  cvt4<<<(E * E / 4 + 255) / 256, 256, 0, stream>>>(w_c, wcb, E * E / 4);

  gemm_bt<2><<<dim3(M / 128, N3 / 128), 256, 0, stream>>>(
      xb, wqb, b_in, nullptr, M, N3, E, Qs, Kc, Vt);
  attn_fwd<<<dim3(8, 128), 256, 0, stream>>>(Qs, Kc, Vt, AO);
  gemm_bt<0><<<dim3(M / 128, E / 128), 256, 0, stream>>>(
      AO, wob, b_out, H1, M, E, E, nullptr, nullptr, nullptr);
  gemm_bt<1><<<dim3(M / 128, E / 128), 256, 0, stream>>>(
      H1, wcb, b_c, out, M, E, E, nullptr, nullptr, nullptr);
}